// Round 1
// baseline (559.898 us; speedup 1.0000x reference)
//
#include <hip/hip_runtime.h>
#include <hip/hip_bf16.h>

#define D 16

// ---------------- Kernel A: per-node linear layers ----------------
// k = x@Wk+bk ; q = x@Wq+bq ; v = x@Wv+bv ; h_base = x@Ws+bs+bias -> d_out
__global__ void node_prep(const float* __restrict__ x,
                          const float* __restrict__ Wk, const float* __restrict__ bk,
                          const float* __restrict__ Wq, const float* __restrict__ bq,
                          const float* __restrict__ Wv, const float* __restrict__ bv,
                          const float* __restrict__ Ws, const float* __restrict__ bs,
                          const float* __restrict__ bias,
                          float* __restrict__ kbuf, float* __restrict__ qbuf,
                          float* __restrict__ vbuf, float* __restrict__ h,
                          int n_nodes) {
    __shared__ float sWk[D * D], sWq[D * D], sWv[D * D], sWs[D * D], sb[4 * D];
    for (int i = threadIdx.x; i < D * D; i += blockDim.x) {
        sWk[i] = Wk[i]; sWq[i] = Wq[i]; sWv[i] = Wv[i]; sWs[i] = Ws[i];
    }
    if (threadIdx.x < D) {
        sb[threadIdx.x]         = bk[threadIdx.x];
        sb[D + threadIdx.x]     = bq[threadIdx.x];
        sb[2 * D + threadIdx.x] = bv[threadIdx.x];
        sb[3 * D + threadIdx.x] = bs[threadIdx.x] + bias[threadIdx.x];
    }
    __syncthreads();
    int n = blockIdx.x * blockDim.x + threadIdx.x;
    if (n >= n_nodes) return;

    float xr[D];
    const float4* xp = (const float4*)(x + (size_t)n * D);
#pragma unroll
    for (int i = 0; i < 4; i++) {
        float4 t = xp[i];
        xr[4 * i + 0] = t.x; xr[4 * i + 1] = t.y; xr[4 * i + 2] = t.z; xr[4 * i + 3] = t.w;
    }
    float kr[D], qr[D], vr[D], hr[D];
#pragma unroll
    for (int c = 0; c < D; c++) {
        kr[c] = sb[c]; qr[c] = sb[D + c]; vr[c] = sb[2 * D + c]; hr[c] = sb[3 * D + c];
    }
#pragma unroll
    for (int j = 0; j < D; j++) {
        float xj = xr[j];
#pragma unroll
        for (int c = 0; c < D; c++) {
            kr[c] = fmaf(xj, sWk[j * D + c], kr[c]);
            qr[c] = fmaf(xj, sWq[j * D + c], qr[c]);
            vr[c] = fmaf(xj, sWv[j * D + c], vr[c]);
            hr[c] = fmaf(xj, sWs[j * D + c], hr[c]);
        }
    }
    float4* kp = (float4*)(kbuf + (size_t)n * D);
    float4* qp = (float4*)(qbuf + (size_t)n * D);
    float4* vp = (float4*)(vbuf + (size_t)n * D);
    float4* hp = (float4*)(h + (size_t)n * D);
#pragma unroll
    for (int i = 0; i < 4; i++) {
        kp[i] = make_float4(kr[4 * i], kr[4 * i + 1], kr[4 * i + 2], kr[4 * i + 3]);
        qp[i] = make_float4(qr[4 * i], qr[4 * i + 1], qr[4 * i + 2], qr[4 * i + 3]);
        vp[i] = make_float4(vr[4 * i], vr[4 * i + 1], vr[4 * i + 2], vr[4 * i + 3]);
        hp[i] = make_float4(hr[4 * i], hr[4 * i + 1], hr[4 * i + 2], hr[4 * i + 3]);
    }
}

// ---------------- Kernel B: per-edge gated message + scatter-add ----------------
// 16 lanes per edge; lane c owns channel c.
__global__ void edge_msg(const int* __restrict__ ei, const float* __restrict__ ea,
                         const float* __restrict__ We,
                         const float* __restrict__ kbuf, const float* __restrict__ qbuf,
                         const float* __restrict__ vbuf,
                         float* __restrict__ h, int n_edges) {
    __shared__ float sWe[D * D];
    for (int i = threadIdx.x; i < D * D; i += blockDim.x) sWe[i] = We[i];
    __syncthreads();

    long long gid = (long long)blockIdx.x * blockDim.x + threadIdx.x;
    long long edge = gid >> 4;
    int c = (int)(gid & (D - 1));
    if (edge >= n_edges) return;

    int src = ei[edge];
    int tgt = ei[(size_t)n_edges + edge];

    // coalesced: 16 contiguous floats per edge
    float eac = ea[(size_t)edge * D + c];
    // e[c] = sum_j ea[j] * We[j][c] via width-16 shuffles
    float ec = 0.f;
#pragma unroll
    for (int j = 0; j < D; j++) {
        float eaj = __shfl(eac, j, D);
        ec = fmaf(eaj, sWe[j * D + c], ec);
    }

    float kk = kbuf[(size_t)tgt * D + c];
    float qq = qbuf[(size_t)src * D + c];
    float vv = vbuf[(size_t)src * D + c];
    float z = kk + ec + qq;
    float gate = 1.f / (1.f + __expf(-z));
    atomicAdd(&h[(size_t)tgt * D + c], gate * vv);
}

// ---------------- Kernel C: BN statistics (sum, sumsq per channel) ----------------
__global__ void bn_stats(const float* __restrict__ h, float* __restrict__ stats,
                         int n_nodes) {
    float s = 0.f, ss = 0.f;
    size_t total = (size_t)n_nodes * D;
    size_t stride = (size_t)gridDim.x * blockDim.x;  // multiple of 16
    for (size_t i = (size_t)blockIdx.x * blockDim.x + threadIdx.x; i < total; i += stride) {
        float val = h[i];
        s += val;
        ss = fmaf(val, val, ss);
    }
    // lanes {l, l^16, l^32, l^48} share the same channel
    s += __shfl_xor(s, 16); s += __shfl_xor(s, 32);
    ss += __shfl_xor(ss, 16); ss += __shfl_xor(ss, 32);

    __shared__ float ls[4 * D], lss[4 * D];
    int wave = threadIdx.x >> 6;
    int lane = threadIdx.x & 63;
    if (lane < D) { ls[wave * D + lane] = s; lss[wave * D + lane] = ss; }
    __syncthreads();
    if (threadIdx.x < D) {
        float ts = 0.f, tss = 0.f;
#pragma unroll
        for (int w = 0; w < 4; w++) { ts += ls[w * D + threadIdx.x]; tss += lss[w * D + threadIdx.x]; }
        atomicAdd(&stats[threadIdx.x], ts);
        atomicAdd(&stats[D + threadIdx.x], tss);
    }
}

// ---------------- Kernel D: normalize + ReLU + residual (in-place on h/out) ----------------
__global__ void bn_finalize(const float* __restrict__ x, const float* __restrict__ stats,
                            const float* __restrict__ gamma, const float* __restrict__ beta,
                            float* __restrict__ out, int n_nodes) {
    __shared__ float sc[D], sh[D];
    if (threadIdx.x < D) {
        float inv_n = 1.f / (float)n_nodes;
        float mean = stats[threadIdx.x] * inv_n;
        float var = stats[D + threadIdx.x] * inv_n - mean * mean;
        float inv = rsqrtf(var + 1e-5f);
        float g = gamma[threadIdx.x] * inv;
        sc[threadIdx.x] = g;
        sh[threadIdx.x] = beta[threadIdx.x] - mean * g;
    }
    __syncthreads();
    size_t i = (size_t)blockIdx.x * blockDim.x + threadIdx.x;
    size_t total = (size_t)n_nodes * D;
    if (i >= total) return;
    int c = (int)(i & (D - 1));
    float t = fmaf(out[i], sc[c], sh[c]);
    out[i] = x[i] + fmaxf(t, 0.f);
}

extern "C" void kernel_launch(void* const* d_in, const int* in_sizes, int n_in,
                              void* d_out, int out_size, void* d_ws, size_t ws_size,
                              hipStream_t stream) {
    const float* x     = (const float*)d_in[0];
    const int*   ei    = (const int*)d_in[1];
    const float* ea    = (const float*)d_in[2];
    const float* Wk    = (const float*)d_in[3];
    const float* bk    = (const float*)d_in[4];
    const float* Wq    = (const float*)d_in[5];
    const float* bq    = (const float*)d_in[6];
    const float* Wv    = (const float*)d_in[7];
    const float* bv    = (const float*)d_in[8];
    const float* We    = (const float*)d_in[9];
    const float* Ws    = (const float*)d_in[10];
    const float* bs    = (const float*)d_in[11];
    const float* bias  = (const float*)d_in[12];
    const float* gamma = (const float*)d_in[13];
    const float* beta  = (const float*)d_in[14];

    int n_nodes = in_sizes[0] / D;
    int n_edges = in_sizes[1] / 2;
    float* out = (float*)d_out;

    float* kbuf  = (float*)d_ws;
    float* qbuf  = kbuf + (size_t)n_nodes * D;
    float* vbuf  = qbuf + (size_t)n_nodes * D;
    float* stats = vbuf + (size_t)n_nodes * D;

    hipMemsetAsync(stats, 0, 2 * D * sizeof(float), stream);

    int nb_nodes = (n_nodes + 255) / 256;
    node_prep<<<nb_nodes, 256, 0, stream>>>(x, Wk, bk, Wq, bq, Wv, bv, Ws, bs, bias,
                                            kbuf, qbuf, vbuf, out, n_nodes);

    long long edge_threads = (long long)n_edges * D;
    int nb_edges = (int)((edge_threads + 255) / 256);
    edge_msg<<<nb_edges, 256, 0, stream>>>(ei, ea, We, kbuf, qbuf, vbuf, out, n_edges);

    bn_stats<<<2048, 256, 0, stream>>>(out, stats, n_nodes);

    size_t total = (size_t)n_nodes * D;
    int nb_fin = (int)((total + 255) / 256);
    bn_finalize<<<nb_fin, 256, 0, stream>>>(x, stats, gamma, beta, out, n_nodes);
}